// Round 12
// baseline (252.437 us; speedup 1.0000x reference)
//
#include <hip/hip_runtime.h>
#include <math.h>

#define N_   325
#define BN_  10400
#define R_   32            // rows per block (2 M-tiles per wave); 10400/32 = 325 exact
#define OUTSZ_ (BN_*12)    // 124800

typedef _Float16 h8v __attribute__((ext_vector_type(8)));  // 8 f16 (4 VGPRs)
typedef _Float16 h2v __attribute__((ext_vector_type(2)));  // 2 f16 (1 VGPR)
typedef float    f4v __attribute__((ext_vector_type(4)));  // 4 fp32 acc

#define L1C  1.4426950408889634f    // log2(e)
#define L2C  2.8853900817779268f    // 2*log2(e)

__device__ __forceinline__ float rcp_f(float x){ return __builtin_amdgcn_rcpf(x); }
#if __has_builtin(__builtin_amdgcn_exp2f)
__device__ __forceinline__ float exp2_f(float x){ return __builtin_amdgcn_exp2f(x); }
#else
__device__ __forceinline__ float exp2_f(float x){ return __expf(x * 0.6931471805599453f); }
#endif

// h-plane [R_][64] f16, 16B blocks XOR-swizzled by row.
__device__ __forceinline__ int plane_idx(int m,int k){
    return m*64 + ((((k>>3)^(m&7))<<3)|(k&7));
}
__device__ __forceinline__ int frag_idx(int m,int kb){   // kb = k/8
    return m*64 + ((kb^(m&7))<<3);
}

// B (Whh) fragments, fp16, PRE-SCALED: r,z rows by -log2e; n rows by -2log2e.
__device__ __forceinline__ void load_B_scaled(const float* __restrict__ Whh,
                                              int jcol, int kg, h8v Bf[3][2])
{
    const float sc[3] = { -L1C, -L1C, -L2C };
#pragma unroll
    for (int g3=0; g3<3; ++g3)
#pragma unroll
        for (int ch=0; ch<2; ++ch) {
            const float* p = Whh + (g3*64 + jcol)*64 + ch*32 + kg*8;
            float4 a = *(const float4*)p;
            float4 b = *(const float4*)(p+4);
            h8v v;
            v[0]=(_Float16)(sc[g3]*a.x); v[1]=(_Float16)(sc[g3]*a.y);
            v[2]=(_Float16)(sc[g3]*a.z); v[3]=(_Float16)(sc[g3]*a.w);
            v[4]=(_Float16)(sc[g3]*b.x); v[5]=(_Float16)(sc[g3]*b.y);
            v[6]=(_Float16)(sc[g3]*b.z); v[7]=(_Float16)(sc[g3]*b.w);
            Bf[g3][ch] = v;
        }
}

__global__ void __launch_bounds__(256, 4) krnn_kernel(
    const float* __restrict__ X,
    const float* __restrict__ eWih, const float* __restrict__ eWhh,
    const float* __restrict__ ebih, const float* __restrict__ ebhh,
    const float* __restrict__ dWih, const float* __restrict__ dWhh,
    const float* __restrict__ dbih, const float* __restrict__ dbhh,
    const float* __restrict__ linW, const float* __restrict__ linb,
    const float* __restrict__ embed, float* __restrict__ ws)
{
    __shared__ _Float16 sH[2][R_*64];                  // 8 KB
    __shared__ float2 sX2[12*R_];                      // [t][m] (x0,x1), 3 KB
    __shared__ float sWgt[R_];

    const int c    = blockIdx.y;
    const int row0 = blockIdx.x * R_;
    const int tid  = threadIdx.x;
    const int lane = tid & 63;
    const int wv   = tid >> 6;
    const int nl   = lane & 15;
    const int kg   = lane >> 4;
    const int jcol = wv*16 + nl;

    // ---------------- prologue ----------------
    for (int i = tid; i < 12*R_; i += 256) {           // sX2[t*R_+m]
        int t = i >> 5, m = i & (R_-1);
        const float* p = X + (size_t)(row0+m)*24 + 2*t;
        sX2[i] = make_float2(p[0], p[1]);
    }
    for (int i = tid; i < R_*64; i += 256) sH[1][i] = (_Float16)0.0f;  // h_{-1}=0
    if (tid < R_) {
        int n = (row0 + tid) % N_;
        float e[10], mx = -1e30f;
#pragma unroll
        for (int cc=0; cc<10; ++cc){ e[cc]=embed[n*10+cc]; mx=fmaxf(mx,e[cc]); }
        float den = 0.0f;
#pragma unroll
        for (int cc=0; cc<10; ++cc) den += exp2_f((e[cc]-mx)*L1C);
        sWgt[tid] = exp2_f((e[c]-mx)*L1C) * rcp_f(den);
    }

    h8v Bf[3][2];
    load_B_scaled(eWhh + c*12288, jcol, kg, Bf);

    // ext B-frags (kg==0 lanes hold k=0,1,2): weights AND biases, pre-scaled.
    // (BeN2 from R9/R11 removed: its product is the lane-constant cbh2e.)
    h8v BeR, BeZ, BeN;
#pragma unroll
    for (int i=0;i<8;++i){ BeR[i]=(_Float16)0.0f; BeZ[i]=(_Float16)0.0f;
                           BeN[i]=(_Float16)0.0f; }
    if (kg == 0) {
        int gc = jcol;
        BeR[0]=(_Float16)(-L1C*eWih[c*384 + gc*2]);
        BeR[1]=(_Float16)(-L1C*eWih[c*384 + gc*2 + 1]);
        BeR[2]=(_Float16)(-L1C*(ebih[c*192+gc] + ebhh[c*192+gc]));
        gc = 64 + jcol;
        BeZ[0]=(_Float16)(-L1C*eWih[c*384 + gc*2]);
        BeZ[1]=(_Float16)(-L1C*eWih[c*384 + gc*2 + 1]);
        BeZ[2]=(_Float16)(-L1C*(ebih[c*192+gc] + ebhh[c*192+gc]));
        gc = 128 + jcol;
        BeN[0]=(_Float16)(-L2C*eWih[c*384 + gc*2]);
        BeN[1]=(_Float16)(-L2C*eWih[c*384 + gc*2 + 1]);
        BeN[2]=(_Float16)(-L2C*ebih[c*192+gc]);
    }
    const float cbh2e = -L2C*ebhh[c*192 + 128 + jcol];   // lane-constant bhh_n term

    // pre-packed x-pairs for Ae slots 0/1: xp[t][Mt] = (f16)x0,(f16)x1 (kg==0 rows)
    h2v xp[12][2];
#pragma unroll
    for (int Mt=0;Mt<2;++Mt) {
        // only kg==0 lanes' values matter; others harmlessly pack their row's x
        for (int t=0; t<12; ++t) {
            float2 xe = sX2[t*R_ + Mt*16 + nl];   // after prologue writes? need sync first
            xp[t][Mt][0] = (_Float16)xe.x; xp[t][Mt][1] = (_Float16)xe.y;
        }
    }
    // NOTE: sX2 was written by this block's prologue; reads above require sync.
    // We re-do the packing after __syncthreads() below to be safe (cheap, once).

    h8v Ae[2];
#pragma unroll
    for (int Mt=0;Mt<2;++Mt){
#pragma unroll
        for (int i=0;i<8;++i) Ae[Mt][i]=(_Float16)0.0f;
        if (kg==0) Ae[Mt][2]=(_Float16)1.0f;
    }

    const f4v Z0 = {0.0f,0.0f,0.0f,0.0f};   // shared zero C operand

    float hreg[2][4];
#pragma unroll
    for (int Mt=0;Mt<2;++Mt)
#pragma unroll
        for (int r4=0;r4<4;++r4) hreg[Mt][r4]=0.0f;

    __syncthreads();

    // redo x packing now that sX2 is guaranteed complete
#pragma unroll
    for (int Mt=0;Mt<2;++Mt)
        for (int t=0; t<12; ++t) {
            float2 xe = sX2[t*R_ + Mt*16 + nl];
            xp[t][Mt][0] = (_Float16)xe.x; xp[t][Mt][1] = (_Float16)xe.y;
        }

    // ---------------- encoder: one step body, unrolled x2 (rp/wp compile-time) ----------------
#define ENC_STEP(T, RP, WP)                                                              \
    {                                                                                    \
        h8v Ah[2][2];                                                                    \
        _Pragma("unroll")                                                                \
        for (int Mt=0; Mt<2; ++Mt)                                                       \
            _Pragma("unroll")                                                            \
            for (int ch=0; ch<2; ++ch)                                                   \
                Ah[Mt][ch] = *(const h8v*)&sH[RP][frag_idx(Mt*16+nl, ch*4+kg)];          \
        if (kg == 0) {                                                                   \
            _Pragma("unroll")                                                            \
            for (int Mt=0; Mt<2; ++Mt) {                                                 \
                Ae[Mt][0] = xp[T][Mt][0]; Ae[Mt][1] = xp[T][Mt][1];                      \
            }                                                                            \
        }                                                                                \
        f4v a0[2], a1[2], a2[2], a3[2];                                                  \
        _Pragma("unroll")                                                                \
        for (int Mt=0;Mt<2;++Mt) {                                                       \
            a0[Mt] = __builtin_amdgcn_mfma_f32_16x16x32_f16(Ae[Mt], BeR,  Z0, 0,0,0);    \
            a1[Mt] = __builtin_amdgcn_mfma_f32_16x16x32_f16(Ae[Mt], BeZ,  Z0, 0,0,0);    \
            a3[Mt] = __builtin_amdgcn_mfma_f32_16x16x32_f16(Ae[Mt], BeN,  Z0, 0,0,0);    \
            a2[Mt] = __builtin_amdgcn_mfma_f32_16x16x32_f16(Ah[Mt][0], Bf[2][0], Z0, 0,0,0); \
            _Pragma("unroll")                                                            \
            for (int ch=0; ch<2; ++ch) {                                                 \
                a0[Mt] = __builtin_amdgcn_mfma_f32_16x16x32_f16(Ah[Mt][ch], Bf[0][ch], a0[Mt],0,0,0); \
                a1[Mt] = __builtin_amdgcn_mfma_f32_16x16x32_f16(Ah[Mt][ch], Bf[1][ch], a1[Mt],0,0,0); \
            }                                                                            \
            a2[Mt] = __builtin_amdgcn_mfma_f32_16x16x32_f16(Ah[Mt][1], Bf[2][1], a2[Mt],0,0,0); \
        }                                                                                \
        _Pragma("unroll")                                                                \
        for (int Mt=0;Mt<2;++Mt)                                                         \
            _Pragma("unroll")                                                            \
            for (int r4=0;r4<4;++r4) {                                                   \
                int m = Mt*16 + kg*4 + r4;                                               \
                float er = exp2_f(a0[Mt][r4]);                                           \
                float rr = rcp_f(1.0f + er);                                             \
                float ez = exp2_f(a1[Mt][r4]);                                           \
                float en = exp2_f(fmaf(rr, a2[Mt][r4] + cbh2e, a3[Mt][r4]));             \
                float h  = hreg[Mt][r4];                                                 \
                float aa = 1.0f + ez;                                                    \
                float den = fmaf(en, aa, aa);                                            \
                float t1 = fmaf(-en, ez, ez);                                            \
                float t2 = fmaf(en, h, h);                                               \
                float hnew = (t1 + t2) * rcp_f(den);                                     \
                hreg[Mt][r4] = hnew;                                                     \
                sH[WP][plane_idx(m,jcol)] = (_Float16)hnew;                              \
            }                                                                            \
        __syncthreads();                                                                 \
    }

#pragma unroll
    for (int tb = 0; tb < 6; ++tb) {
        ENC_STEP(2*tb,   1, 0)
        ENC_STEP(2*tb+1, 0, 1)
    }
#undef ENC_STEP

    // ---------------- decoder setup ----------------
    load_B_scaled(dWhh + c*12288, jcol, kg, Bf);
    h8v Blw[2];                       // B = linW replicated over n-cols
#pragma unroll
    for (int ch=0; ch<2; ++ch) {
        const float* p = linW + c*64 + ch*32 + kg*8;
        float4 a = *(const float4*)p;
        float4 b = *(const float4*)(p+4);
        h8v v;
        v[0]=(_Float16)a.x; v[1]=(_Float16)a.y; v[2]=(_Float16)a.z; v[3]=(_Float16)a.w;
        v[4]=(_Float16)b.x; v[5]=(_Float16)b.y; v[6]=(_Float16)b.z; v[7]=(_Float16)b.w;
        Blw[ch] = v;
    }
    float dws0, ks0, dws1, ks1, dwn2, kn, cbh2;
    {
        int gc = jcol;
        dws0 = -L1C*dWih[c*192 + gc];
        ks0  = -L1C*(dbih[c*192 + gc] + dbhh[c*192 + gc]);
        gc = 64 + jcol;
        dws1 = -L1C*dWih[c*192 + gc];
        ks1  = -L1C*(dbih[c*192 + gc] + dbhh[c*192 + gc]);
        gc = 128 + jcol;
        dwn2 = -L2C*dWih[c*192 + gc];
        kn   = -L2C*dbih[c*192 + gc];
        cbh2 = -L2C*dbhh[c*192 + gc];
    }
    const float lb = linb[c];
    float* __restrict__ wsc = ws + (size_t)c * OUTSZ_;

    float lvx[2][4];                  // lv for s=0: last observed feature 0
#pragma unroll
    for (int Mt=0;Mt<2;++Mt)
#pragma unroll
        for (int r4=0;r4<4;++r4)
            lvx[Mt][r4] = sX2[11*R_ + Mt*16 + kg*4 + r4].x;

    // ---------------- decoder: one step body, unrolled x2 ----------------
#define DEC_STEP(S, RP, WP)                                                              \
    {                                                                                    \
        h8v Ah[2][2];                                                                    \
        _Pragma("unroll")                                                                \
        for (int Mt=0; Mt<2; ++Mt)                                                       \
            _Pragma("unroll")                                                            \
            for (int ch=0; ch<2; ++ch)                                                   \
                Ah[Mt][ch] = *(const h8v*)&sH[RP][frag_idx(Mt*16+nl, ch*4+kg)];          \
        f4v a0[2], a1[2], a2[2], av[2];                                                  \
        _Pragma("unroll")                                                                \
        for (int Mt=0;Mt<2;++Mt) {                                                       \
            a0[Mt] = __builtin_amdgcn_mfma_f32_16x16x32_f16(Ah[Mt][0], Bf[0][0], Z0, 0,0,0); \
            a1[Mt] = __builtin_amdgcn_mfma_f32_16x16x32_f16(Ah[Mt][0], Bf[1][0], Z0, 0,0,0); \
            a2[Mt] = __builtin_amdgcn_mfma_f32_16x16x32_f16(Ah[Mt][0], Bf[2][0], Z0, 0,0,0); \
            a0[Mt] = __builtin_amdgcn_mfma_f32_16x16x32_f16(Ah[Mt][1], Bf[0][1], a0[Mt],0,0,0); \
            a1[Mt] = __builtin_amdgcn_mfma_f32_16x16x32_f16(Ah[Mt][1], Bf[1][1], a1[Mt],0,0,0); \
            a2[Mt] = __builtin_amdgcn_mfma_f32_16x16x32_f16(Ah[Mt][1], Bf[2][1], a2[Mt],0,0,0); \
        }                                                                                \
        if (S > 0) {                                                                     \
            _Pragma("unroll")                                                            \
            for (int Mt=0;Mt<2;++Mt) {                                                   \
                av[Mt] = __builtin_amdgcn_mfma_f32_16x16x32_f16(Ah[Mt][0], Blw[0], Z0, 0,0,0); \
                av[Mt] = __builtin_amdgcn_mfma_f32_16x16x32_f16(Ah[Mt][1], Blw[1], av[Mt],0,0,0); \
            }                                                                            \
        }                                                                                \
        _Pragma("unroll")                                                                \
        for (int Mt=0;Mt<2;++Mt)                                                         \
            _Pragma("unroll")                                                            \
            for (int r4=0;r4<4;++r4) {                                                   \
                int m = Mt*16 + kg*4 + r4;                                               \
                float lv;                                                                \
                if (S == 0) lv = lvx[Mt][r4];                                            \
                else {                                                                   \
                    lv = av[Mt][r4] + lb;                                                \
                    if (wv == 0 && nl == 0)                                              \
                        wsc[(size_t)(row0+m)*12 + (S-1)] = sWgt[m]*lv;                   \
                }                                                                        \
                float er = exp2_f(a0[Mt][r4] + fmaf(dws0, lv, ks0));                     \
                float rr = rcp_f(1.0f + er);                                             \
                float ez = exp2_f(a1[Mt][r4] + fmaf(dws1, lv, ks1));                     \
                float en = exp2_f(fmaf(rr, a2[Mt][r4] + cbh2, fmaf(dwn2, lv, kn)));      \
                float h  = hreg[Mt][r4];                                                 \
                float aa = 1.0f + ez;                                                    \
                float den = fmaf(en, aa, aa);                                            \
                float t1 = fmaf(-en, ez, ez);                                            \
                float t2 = fmaf(en, h, h);                                               \
                float hnew = (t1 + t2) * rcp_f(den);                                     \
                hreg[Mt][r4] = hnew;                                                     \
                sH[WP][plane_idx(m,jcol)] = (_Float16)hnew;                              \
            }                                                                            \
        __syncthreads();                                                                 \
    }

    DEC_STEP(0, 1, 0)
    DEC_STEP(1, 0, 1)
#pragma unroll
    for (int sb = 1; sb < 6; ++sb) {
        DEC_STEP(2*sb,   1, 0)
        DEC_STEP(2*sb+1, 0, 1)
    }
#undef DEC_STEP

    // ---------------- epilogue: v_11 from h_11 (written to buf 1) ----------------
    {
        f4v av[2];
#pragma unroll
        for (int Mt=0; Mt<2; ++Mt) {
            h8v A0 = *(const h8v*)&sH[1][frag_idx(Mt*16+nl, 0*4+kg)];
            h8v A1 = *(const h8v*)&sH[1][frag_idx(Mt*16+nl, 1*4+kg)];
            av[Mt] = __builtin_amdgcn_mfma_f32_16x16x32_f16(A0, Blw[0], Z0, 0,0,0);
            av[Mt] = __builtin_amdgcn_mfma_f32_16x16x32_f16(A1, Blw[1], av[Mt],0,0,0);
        }
        if (wv == 0 && nl == 0) {
#pragma unroll
            for (int Mt=0;Mt<2;++Mt)
#pragma unroll
                for (int r4=0;r4<4;++r4) {
                    int m = Mt*16 + kg*4 + r4;
                    wsc[(size_t)(row0+m)*12 + 11] = sWgt[m]*(av[Mt][r4] + lb);
                }
        }
    }
}

// Mix over clusters: out[i] = sum_c ws[c][i]. ws is 5 MB, L2/L3-hot.
__global__ void __launch_bounds__(256) mix_kernel(const float* __restrict__ ws,
                                                  float* __restrict__ out)
{
    int i = blockIdx.x * 256 + threadIdx.x;
    if (i < OUTSZ_) {
        float s = 0.0f;
#pragma unroll
        for (int c = 0; c < 10; ++c) s += ws[(size_t)c * OUTSZ_ + i];
        out[i] = s;
    }
}

extern "C" void kernel_launch(void* const* d_in, const int* in_sizes, int n_in,
                              void* d_out, int out_size, void* d_ws, size_t ws_size,
                              hipStream_t stream) {
    // 0:A 1:X 2:enc_Wih 3:enc_Whh 4:enc_bih 5:enc_bhh
    // 6:dec_Wih 7:dec_Whh 8:dec_bih 9:dec_bhh 10:lin_W 11:lin_b 12:embed
    const float* X    = (const float*)d_in[1];
    const float* eWih = (const float*)d_in[2];
    const float* eWhh = (const float*)d_in[3];
    const float* ebih = (const float*)d_in[4];
    const float* ebhh = (const float*)d_in[5];
    const float* dWih = (const float*)d_in[6];
    const float* dWhh = (const float*)d_in[7];
    const float* dbih = (const float*)d_in[8];
    const float* dbhh = (const float*)d_in[9];
    const float* linW = (const float*)d_in[10];
    const float* linb = (const float*)d_in[11];
    const float* emb  = (const float*)d_in[12];
    float* ws  = (float*)d_ws;
    float* out = (float*)d_out;

    dim3 grid(BN_ / R_, 10);   // 325 x 10 blocks
    krnn_kernel<<<grid, dim3(256), 0, stream>>>(
        X, eWih, eWhh, ebih, ebhh, dWih, dWhh, dbih, dbhh, linW, linb, emb, ws);
    mix_kernel<<<(OUTSZ_ + 255) / 256, dim3(256), 0, stream>>>(ws, out);
}

// Round 13
// 226.311 us; speedup vs baseline: 1.1154x; 1.1154x over previous
//
#include <hip/hip_runtime.h>
#include <math.h>

#define N_   325
#define BN_  10400
#define R_   32            // rows per block (2 M-tiles per wave); 10400/32 = 325 exact
#define OUTSZ_ (BN_*12)    // 124800

typedef _Float16 h8v __attribute__((ext_vector_type(8)));  // 8 f16 (4 VGPRs)
typedef float    f4v __attribute__((ext_vector_type(4)));  // 4 fp32 acc

#define L1C  1.4426950408889634f    // log2(e)
#define L2C  2.8853900817779268f    // 2*log2(e)

__device__ __forceinline__ float rcp_f(float x){ return __builtin_amdgcn_rcpf(x); }
#if __has_builtin(__builtin_amdgcn_exp2f)
__device__ __forceinline__ float exp2_f(float x){ return __builtin_amdgcn_exp2f(x); }
#else
__device__ __forceinline__ float exp2_f(float x){ return __expf(x * 0.6931471805599453f); }
#endif

// h-plane [R_][64] f16, 16B blocks XOR-swizzled by row.
__device__ __forceinline__ int plane_idx(int m,int k){
    return m*64 + ((((k>>3)^(m&7))<<3)|(k&7));
}
__device__ __forceinline__ int frag_idx(int m,int kb){   // kb = k/8
    return m*64 + ((kb^(m&7))<<3);
}

// B (Whh) fragments, fp16, PRE-SCALED: r,z rows by -log2e; n rows by -2log2e.
__device__ __forceinline__ void load_B_scaled(const float* __restrict__ Whh,
                                              int jcol, int kg, h8v Bf[3][2])
{
    const float sc[3] = { -L1C, -L1C, -L2C };
#pragma unroll
    for (int g3=0; g3<3; ++g3)
#pragma unroll
        for (int ch=0; ch<2; ++ch) {
            const float* p = Whh + (g3*64 + jcol)*64 + ch*32 + kg*8;
            float4 a = *(const float4*)p;
            float4 b = *(const float4*)(p+4);
            h8v v;
            v[0]=(_Float16)(sc[g3]*a.x); v[1]=(_Float16)(sc[g3]*a.y);
            v[2]=(_Float16)(sc[g3]*a.z); v[3]=(_Float16)(sc[g3]*a.w);
            v[4]=(_Float16)(sc[g3]*b.x); v[5]=(_Float16)(sc[g3]*b.y);
            v[6]=(_Float16)(sc[g3]*b.z); v[7]=(_Float16)(sc[g3]*b.w);
            Bf[g3][ch] = v;
        }
}

// R11 structure (measured optimum of this design space): 256 thr = 4 waves,
// 32 rows, one cluster c; fp16 MFMA with gi/biases folded via ext-MFMA; fp32
// carry; 1 barrier/step; 5-trans gate algebra (shared rcp for z/tanh:
// hnew = (ez(1-en) + h(1+en)) / ((1+en)(1+ez))); no atomics/memset — stores
// to ws[c][bn][t], mixed by a tiny second kernel.
// DO NOT add persistent per-lane state: the 128-reg unified budget is full
// (R5/R10/R12 all spilled: WRITE_SIZE 110-150 MB signature).
__global__ void __launch_bounds__(256, 4) krnn_kernel(
    const float* __restrict__ X,
    const float* __restrict__ eWih, const float* __restrict__ eWhh,
    const float* __restrict__ ebih, const float* __restrict__ ebhh,
    const float* __restrict__ dWih, const float* __restrict__ dWhh,
    const float* __restrict__ dbih, const float* __restrict__ dbhh,
    const float* __restrict__ linW, const float* __restrict__ linb,
    const float* __restrict__ embed, float* __restrict__ ws)
{
    __shared__ _Float16 sH[2][R_*64];                  // 8 KB
    __shared__ float2 sX2[12*R_];                      // [t][m] (x0,x1), 3 KB
    __shared__ float sWgt[R_];

    const int c    = blockIdx.y;
    const int row0 = blockIdx.x * R_;
    const int tid  = threadIdx.x;
    const int lane = tid & 63;
    const int wv   = tid >> 6;
    const int nl   = lane & 15;
    const int kg   = lane >> 4;
    const int jcol = wv*16 + nl;

    // ---------------- prologue ----------------
    for (int i = tid; i < 12*R_; i += 256) {           // sX2[t*R_+m]
        int t = i >> 5, m = i & (R_-1);
        const float* p = X + (size_t)(row0+m)*24 + 2*t;
        sX2[i] = make_float2(p[0], p[1]);
    }
    for (int i = tid; i < R_*64; i += 256) sH[1][i] = (_Float16)0.0f;  // h_{-1}=0
    if (tid < R_) {
        int n = (row0 + tid) % N_;
        float e[10], mx = -1e30f;
#pragma unroll
        for (int cc=0; cc<10; ++cc){ e[cc]=embed[n*10+cc]; mx=fmaxf(mx,e[cc]); }
        float den = 0.0f;
#pragma unroll
        for (int cc=0; cc<10; ++cc) den += exp2_f((e[cc]-mx)*L1C);
        sWgt[tid] = exp2_f((e[c]-mx)*L1C) * rcp_f(den);
    }

    h8v Bf[3][2];
    load_B_scaled(eWhh + c*12288, jcol, kg, Bf);

    // ext B-frags (kg==0 lanes hold k=0,1,2): weights AND biases, pre-scaled.
    h8v BeR, BeZ, BeN, BeN2;
#pragma unroll
    for (int i=0;i<8;++i){ BeR[i]=(_Float16)0.0f; BeZ[i]=(_Float16)0.0f;
                           BeN[i]=(_Float16)0.0f; BeN2[i]=(_Float16)0.0f; }
    if (kg == 0) {
        int gc = jcol;
        BeR[0]=(_Float16)(-L1C*eWih[c*384 + gc*2]);
        BeR[1]=(_Float16)(-L1C*eWih[c*384 + gc*2 + 1]);
        BeR[2]=(_Float16)(-L1C*(ebih[c*192+gc] + ebhh[c*192+gc]));
        gc = 64 + jcol;
        BeZ[0]=(_Float16)(-L1C*eWih[c*384 + gc*2]);
        BeZ[1]=(_Float16)(-L1C*eWih[c*384 + gc*2 + 1]);
        BeZ[2]=(_Float16)(-L1C*(ebih[c*192+gc] + ebhh[c*192+gc]));
        gc = 128 + jcol;
        BeN[0]=(_Float16)(-L2C*eWih[c*384 + gc*2]);
        BeN[1]=(_Float16)(-L2C*eWih[c*384 + gc*2 + 1]);
        BeN[2]=(_Float16)(-L2C*ebih[c*192+gc]);
        BeN2[2]=(_Float16)(-L2C*ebhh[c*192+gc]);
    }
    // A-ext: [x0,x1,1,0..] for kg==0 lanes; slots 0/1 updated per step.
    h8v Ae[2];
#pragma unroll
    for (int Mt=0;Mt<2;++Mt){
#pragma unroll
        for (int i=0;i<8;++i) Ae[Mt][i]=(_Float16)0.0f;
        if (kg==0) Ae[Mt][2]=(_Float16)1.0f;
    }

    const f4v Z0 = {0.0f,0.0f,0.0f,0.0f};   // shared zero C operand

    float hreg[2][4];
#pragma unroll
    for (int Mt=0;Mt<2;++Mt)
#pragma unroll
        for (int r4=0;r4<4;++r4) hreg[Mt][r4]=0.0f;

    __syncthreads();

    // ---------------- encoder steps 0..11 (t=0 uses zeroed plane) ----------------
    for (int t = 0; t < 12; ++t) {
        const int rp = (t+1)&1, wp = t&1;
        h8v Ah[2][2];
#pragma unroll
        for (int Mt=0; Mt<2; ++Mt)
#pragma unroll
            for (int ch=0; ch<2; ++ch)
                Ah[Mt][ch] = *(const h8v*)&sH[rp][frag_idx(Mt*16+nl, ch*4+kg)];

        if (kg == 0) {
#pragma unroll
            for (int Mt=0; Mt<2; ++Mt) {
                float2 xe = sX2[t*R_ + Mt*16 + nl];
                Ae[Mt][0] = (_Float16)xe.x; Ae[Mt][1] = (_Float16)xe.y;
            }
        }

        f4v a0[2], a1[2], a2[2], a3[2];
#pragma unroll
        for (int Mt=0;Mt<2;++Mt) {
            a0[Mt] = __builtin_amdgcn_mfma_f32_16x16x32_f16(Ae[Mt], BeR,  Z0, 0,0,0);
            a1[Mt] = __builtin_amdgcn_mfma_f32_16x16x32_f16(Ae[Mt], BeZ,  Z0, 0,0,0);
            a2[Mt] = __builtin_amdgcn_mfma_f32_16x16x32_f16(Ae[Mt], BeN2, Z0, 0,0,0);
            a3[Mt] = __builtin_amdgcn_mfma_f32_16x16x32_f16(Ae[Mt], BeN,  Z0, 0,0,0);
#pragma unroll
            for (int ch=0; ch<2; ++ch) {
                a0[Mt] = __builtin_amdgcn_mfma_f32_16x16x32_f16(Ah[Mt][ch], Bf[0][ch], a0[Mt],0,0,0);
                a1[Mt] = __builtin_amdgcn_mfma_f32_16x16x32_f16(Ah[Mt][ch], Bf[1][ch], a1[Mt],0,0,0);
                a2[Mt] = __builtin_amdgcn_mfma_f32_16x16x32_f16(Ah[Mt][ch], Bf[2][ch], a2[Mt],0,0,0);
            }
        }

#pragma unroll
        for (int Mt=0;Mt<2;++Mt)
#pragma unroll
            for (int r4=0;r4<4;++r4) {
                int m = Mt*16 + kg*4 + r4;
                float er = exp2_f(a0[Mt][r4]);
                float rr = rcp_f(1.0f + er);
                float ez = exp2_f(a1[Mt][r4]);
                float en = exp2_f(fmaf(rr, a2[Mt][r4], a3[Mt][r4]));
                float h  = hreg[Mt][r4];
                float aa = 1.0f + ez;
                float den = fmaf(en, aa, aa);        // (1+en)(1+ez)
                float t1 = fmaf(-en, ez, ez);        // ez(1-en)
                float t2 = fmaf(en, h, h);           // h(1+en)
                float hnew = (t1 + t2) * rcp_f(den);
                hreg[Mt][r4] = hnew;
                sH[wp][plane_idx(m,jcol)] = (_Float16)hnew;
            }
        __syncthreads();
    }

    // ---------------- decoder setup ----------------
    load_B_scaled(dWhh + c*12288, jcol, kg, Bf);
    h8v Blw[2];                       // B = linW replicated over n-cols
#pragma unroll
    for (int ch=0; ch<2; ++ch) {
        const float* p = linW + c*64 + ch*32 + kg*8;
        float4 a = *(const float4*)p;
        float4 b = *(const float4*)(p+4);
        h8v v;
        v[0]=(_Float16)a.x; v[1]=(_Float16)a.y; v[2]=(_Float16)a.z; v[3]=(_Float16)a.w;
        v[4]=(_Float16)b.x; v[5]=(_Float16)b.y; v[6]=(_Float16)b.z; v[7]=(_Float16)b.w;
        Blw[ch] = v;
    }
    float dws0, ks0, dws1, ks1, dwn2, kn, cbh2;
    {
        int gc = jcol;
        dws0 = -L1C*dWih[c*192 + gc];
        ks0  = -L1C*(dbih[c*192 + gc] + dbhh[c*192 + gc]);
        gc = 64 + jcol;
        dws1 = -L1C*dWih[c*192 + gc];
        ks1  = -L1C*(dbih[c*192 + gc] + dbhh[c*192 + gc]);
        gc = 128 + jcol;
        dwn2 = -L2C*dWih[c*192 + gc];
        kn   = -L2C*dbih[c*192 + gc];
        cbh2 = -L2C*dbhh[c*192 + gc];
    }
    const float lb = linb[c];
    float* __restrict__ wsc = ws + (size_t)c * OUTSZ_;

    float lvx[2][4];                  // lv for s=0: last observed feature 0
#pragma unroll
    for (int Mt=0;Mt<2;++Mt)
#pragma unroll
        for (int r4=0;r4<4;++r4)
            lvx[Mt][r4] = sX2[11*R_ + Mt*16 + kg*4 + r4].x;

    // ---------------- decoder: 12 steps ----------------
    for (int s = 0; s < 12; ++s) {
        const int rp = (s+1)&1, wp = s&1;
        h8v Ah[2][2];
#pragma unroll
        for (int Mt=0; Mt<2; ++Mt)
#pragma unroll
            for (int ch=0; ch<2; ++ch)
                Ah[Mt][ch] = *(const h8v*)&sH[rp][frag_idx(Mt*16+nl, ch*4+kg)];

        f4v a0[2], a1[2], a2[2], av[2];
#pragma unroll
        for (int Mt=0;Mt<2;++Mt) {
            a0[Mt] = __builtin_amdgcn_mfma_f32_16x16x32_f16(Ah[Mt][0], Bf[0][0], Z0, 0,0,0);
            a1[Mt] = __builtin_amdgcn_mfma_f32_16x16x32_f16(Ah[Mt][0], Bf[1][0], Z0, 0,0,0);
            a2[Mt] = __builtin_amdgcn_mfma_f32_16x16x32_f16(Ah[Mt][0], Bf[2][0], Z0, 0,0,0);
            a0[Mt] = __builtin_amdgcn_mfma_f32_16x16x32_f16(Ah[Mt][1], Bf[0][1], a0[Mt],0,0,0);
            a1[Mt] = __builtin_amdgcn_mfma_f32_16x16x32_f16(Ah[Mt][1], Bf[1][1], a1[Mt],0,0,0);
            a2[Mt] = __builtin_amdgcn_mfma_f32_16x16x32_f16(Ah[Mt][1], Bf[2][1], a2[Mt],0,0,0);
        }
        if (s > 0) {
#pragma unroll
            for (int Mt=0;Mt<2;++Mt) {
                av[Mt] = __builtin_amdgcn_mfma_f32_16x16x32_f16(Ah[Mt][0], Blw[0], Z0, 0,0,0);
                av[Mt] = __builtin_amdgcn_mfma_f32_16x16x32_f16(Ah[Mt][1], Blw[1], av[Mt],0,0,0);
            }
        }

#pragma unroll
        for (int Mt=0;Mt<2;++Mt)
#pragma unroll
            for (int r4=0;r4<4;++r4) {
                int m = Mt*16 + kg*4 + r4;
                float lv;
                if (s == 0) lv = lvx[Mt][r4];
                else {
                    lv = av[Mt][r4] + lb;          // v_{s-1} = lin(h_{s-1})
                    if (wv == 0 && nl == 0)
                        wsc[(size_t)(row0+m)*12 + (s-1)] = sWgt[m]*lv;
                }
                float er = exp2_f(a0[Mt][r4] + fmaf(dws0, lv, ks0));
                float rr = rcp_f(1.0f + er);
                float ez = exp2_f(a1[Mt][r4] + fmaf(dws1, lv, ks1));
                float en = exp2_f(fmaf(rr, a2[Mt][r4] + cbh2, fmaf(dwn2, lv, kn)));
                float h  = hreg[Mt][r4];
                float aa = 1.0f + ez;
                float den = fmaf(en, aa, aa);
                float t1 = fmaf(-en, ez, ez);
                float t2 = fmaf(en, h, h);
                float hnew = (t1 + t2) * rcp_f(den);
                hreg[Mt][r4] = hnew;
                sH[wp][plane_idx(m,jcol)] = (_Float16)hnew;
            }
        __syncthreads();
    }

    // ---------------- epilogue: v_11 from h_11 (buf (12+1)&1 = 1) ----------------
    {
        f4v av[2];
#pragma unroll
        for (int Mt=0; Mt<2; ++Mt) {
            h8v A0 = *(const h8v*)&sH[1][frag_idx(Mt*16+nl, 0*4+kg)];
            h8v A1 = *(const h8v*)&sH[1][frag_idx(Mt*16+nl, 1*4+kg)];
            av[Mt] = __builtin_amdgcn_mfma_f32_16x16x32_f16(A0, Blw[0], Z0, 0,0,0);
            av[Mt] = __builtin_amdgcn_mfma_f32_16x16x32_f16(A1, Blw[1], av[Mt],0,0,0);
        }
        if (wv == 0 && nl == 0) {
#pragma unroll
            for (int Mt=0;Mt<2;++Mt)
#pragma unroll
                for (int r4=0;r4<4;++r4) {
                    int m = Mt*16 + kg*4 + r4;
                    wsc[(size_t)(row0+m)*12 + 11] = sWgt[m]*(av[Mt][r4] + lb);
                }
        }
    }
}

// Mix over clusters: out[i] = sum_c ws[c][i]. ws is 5 MB, L2/L3-hot.
__global__ void __launch_bounds__(256) mix_kernel(const float* __restrict__ ws,
                                                  float* __restrict__ out)
{
    int i = blockIdx.x * 256 + threadIdx.x;
    if (i < OUTSZ_) {
        float s = 0.0f;
#pragma unroll
        for (int c = 0; c < 10; ++c) s += ws[(size_t)c * OUTSZ_ + i];
        out[i] = s;
    }
}

extern "C" void kernel_launch(void* const* d_in, const int* in_sizes, int n_in,
                              void* d_out, int out_size, void* d_ws, size_t ws_size,
                              hipStream_t stream) {
    // 0:A 1:X 2:enc_Wih 3:enc_Whh 4:enc_bih 5:enc_bhh
    // 6:dec_Wih 7:dec_Whh 8:dec_bih 9:dec_bhh 10:lin_W 11:lin_b 12:embed
    const float* X    = (const float*)d_in[1];
    const float* eWih = (const float*)d_in[2];
    const float* eWhh = (const float*)d_in[3];
    const float* ebih = (const float*)d_in[4];
    const float* ebhh = (const float*)d_in[5];
    const float* dWih = (const float*)d_in[6];
    const float* dWhh = (const float*)d_in[7];
    const float* dbih = (const float*)d_in[8];
    const float* dbhh = (const float*)d_in[9];
    const float* linW = (const float*)d_in[10];
    const float* linb = (const float*)d_in[11];
    const float* emb  = (const float*)d_in[12];
    float* ws  = (float*)d_ws;
    float* out = (float*)d_out;

    dim3 grid(BN_ / R_, 10);   // 325 x 10 blocks
    krnn_kernel<<<grid, dim3(256), 0, stream>>>(
        X, eWih, eWhh, ebih, ebhh, dWih, dWhh, dbih, dbhh, linW, linb, emb, ws);
    mix_kernel<<<(OUTSZ_ + 255) / 256, dim3(256), 0, stream>>>(ws, out);
}